// Round 10
// baseline (287.356 us; speedup 1.0000x reference)
//
#include <hip/hip_runtime.h>
#include <hip/hip_bf16.h>

#define N_NODES 10000
#define N_EDGES 320000
#define D 256

typedef __attribute__((ext_vector_type(8))) _Float16 f16x8;
typedef __attribute__((ext_vector_type(4))) _Float16 f16x4;
typedef __attribute__((ext_vector_type(4))) float f32x4;

__device__ __forceinline__ void async_copy16(const void* g, void* l) {
  __builtin_amdgcn_global_load_lds(
      (const __attribute__((address_space(1))) unsigned int*)g,
      (__attribute__((address_space(3))) unsigned int*)l, 16, 0, 0);
}

// stage ROWS x 32 f16 k-chunk into Bs[ROWS*32] with XOR quad swizzle; WAVES waves cooperate
template<int ROWS, int WAVES>
__device__ __forceinline__ void stage_tile(const _Float16* __restrict__ Wb, int k0, int K,
                                           _Float16* Bs, int wave, int lane) {
  const int sr = lane >> 2, ss = lane & 3;
#pragma unroll
  for (int grp = wave; grp < ROWS / 16; grp += WAVES) {
    int r = grp * 16 + sr;
    int gq = ss ^ ((r >> 1) & 3);
    async_copy16(Wb + (size_t)r * K + k0 + gq * 8, Bs + grp * 512);
  }
}
__device__ __forceinline__ f16x8 read_B(const _Float16* Bs, int r, int quad) {
  return *(const f16x8*)(Bs + r * 32 + (quad ^ ((r >> 1) & 3)) * 8);
}

__device__ __forceinline__ float fast_sigmoid(float x) {
  return __builtin_amdgcn_rcpf(1.f + __expf(-x));
}
__device__ __forceinline__ float fast_tanh(float x) {
  float ax = fabsf(x);
  float e = __expf(-2.f * ax);
  float t = (1.f - e) * __builtin_amdgcn_rcpf(1.f + e);
  return copysignf(t, x);
}

// ---------- prep: cast weights to fp16; Wg packed as (i,g,o) 16-col triples; hist ----------
__global__ void prep_kernel(const float* __restrict__ W_rel, const float* __restrict__ W_ih,
                            const float* __restrict__ b_ih, const float* __restrict__ b_hh,
                            const float* __restrict__ W1, const float* __restrict__ W2,
                            const float* __restrict__ W3,
                            const int* __restrict__ dst, int* __restrict__ cnt,
                            _Float16* W_relh, _Float16* Wg, float* bg,
                            _Float16* W1h, _Float16* W2h, _Float16* W3h) {
  int i = blockIdx.x * 256 + threadIdx.x;
  if (i < N_EDGES) { atomicAdd(&cnt[dst[i]], 1); return; }
  i -= N_EDGES;
  if (i < 131072) { W_relh[i] = (_Float16)W_rel[i]; return; }
  i -= 131072;
  if (i < 196608) {
    // packed row p = 48t + 16*phase + u  ->  W_ih row (16t+u) + {0,512,768}[phase]
    int p = i >> 8, k = i & 255;
    int t = p / 48, rem = p - t * 48;
    int phase = rem >> 4, u = rem & 15;
    int orig = t * 16 + u + (phase == 1 ? 512 : (phase == 2 ? 768 : 0));
    Wg[i] = (_Float16)W_ih[orig * 256 + k]; return;
  }
  i -= 196608;
  if (i < 32768) { W1h[i] = (_Float16)W1[i]; return; }
  i -= 32768;
  if (i < 16384) { W2h[i] = (_Float16)W2[i]; return; }
  i -= 16384;
  if (i < 32768) { W3h[i] = (_Float16)W3[i]; return; }
  i -= 32768;
  if (i < 768) {
    int t = i / 48, rem = i - t * 48;
    int phase = rem >> 4, u = rem & 15;
    int orig = t * 16 + u + (phase == 1 ? 512 : (phase == 2 ? 768 : 0));
    bg[i] = b_ih[orig] + b_hh[orig];
  }
}

// ---------- scan ----------
__global__ __launch_bounds__(1024) void scan_kernel(const int* __restrict__ cnt,
                                                    int* __restrict__ offs,
                                                    int* __restrict__ cursors, int n) {
  __shared__ int buf[1024];
  const int t = threadIdx.x;
  int loc[10];
  int s = 0;
  int base = t * 10;
#pragma unroll
  for (int q = 0; q < 10; ++q) {
    int i = base + q;
    int v = (i < n) ? cnt[i] : 0;
    loc[q] = s;
    s += v;
  }
  buf[t] = s;
  __syncthreads();
  for (int off = 1; off < 1024; off <<= 1) {
    int x = (t >= off) ? buf[t - off] : 0;
    __syncthreads();
    buf[t] += x;
    __syncthreads();
  }
  int excl = buf[t] - s;
#pragma unroll
  for (int q = 0; q < 10; ++q) {
    int i = base + q;
    if (i < n) { int o = excl + loc[q]; offs[i] = o; cursors[i] = o; }
  }
  if (t == 1023) offs[n] = buf[1023];
}

// ---------- fill ----------
__global__ void fill_kernel(const int* __restrict__ dst, const int* __restrict__ src,
                            const int* __restrict__ rel, int* __restrict__ cursors,
                            unsigned int* __restrict__ rowoff) {
  int e = blockIdx.x * blockDim.x + threadIdx.x;
  if (e < N_EDGES) {
    int pos = atomicAdd(&cursors[dst[e]], 1);
    rowoff[pos] = (unsigned int)((rel[e] * N_NODES + src[e]) * D);
  }
}

// ---------- fused edge NN (unchanged from R9): 512 threads, LDS-staged W ----------
__global__ __launch_bounds__(512) void edge_fused(
    const float* __restrict__ feat, const _Float16* __restrict__ W_relh,
    const float* __restrict__ b_rel, _Float16* __restrict__ Mh)
{
  __shared__ _Float16 Hs[64 * 266];
  __shared__ alignas(16) _Float16 Bs[256 * 32];
  const int t = threadIdx.x;
  const int wave = t >> 6, lane = t & 63;
  const int quad = lane >> 4, lrow = lane & 15;
  const int z = blockIdx.y;
  const int m0 = blockIdx.x * 64;
  const _Float16* Wb = W_relh + z * 65536;
  const float* bb = b_rel + z * 256;
  const int wm = (wave >> 2) * 32;
  const int wn = (wave & 3) * 64;

  int ar0 = m0 + wm + lrow;      if (ar0 > N_NODES - 1) ar0 = N_NODES - 1;
  int ar1 = m0 + wm + 16 + lrow; if (ar1 > N_NODES - 1) ar1 = N_NODES - 1;
  const float* fr0 = feat + (size_t)ar0 * 256;
  const float* fr1 = feat + (size_t)ar1 * 256;

  f32x4 acc[2][4];
#pragma unroll
  for (int i = 0; i < 2; ++i)
#pragma unroll
    for (int j = 0; j < 4; ++j) acc[i][j] = (f32x4)0.0f;

#pragma unroll
  for (int kc = 0; kc < 8; ++kc) {
    stage_tile<256, 8>(Wb, kc * 32, 256, Bs, wave, lane);
    float4 u0 = *(const float4*)(fr0 + kc * 32 + quad * 8);
    float4 u1 = *(const float4*)(fr0 + kc * 32 + quad * 8 + 4);
    float4 v0 = *(const float4*)(fr1 + kc * 32 + quad * 8);
    float4 v1 = *(const float4*)(fr1 + kc * 32 + quad * 8 + 4);
    f16x8 af0, af1;
    af0[0] = (_Float16)u0.x; af0[1] = (_Float16)u0.y; af0[2] = (_Float16)u0.z; af0[3] = (_Float16)u0.w;
    af0[4] = (_Float16)u1.x; af0[5] = (_Float16)u1.y; af0[6] = (_Float16)u1.z; af0[7] = (_Float16)u1.w;
    af1[0] = (_Float16)v0.x; af1[1] = (_Float16)v0.y; af1[2] = (_Float16)v0.z; af1[3] = (_Float16)v0.w;
    af1[4] = (_Float16)v1.x; af1[5] = (_Float16)v1.y; af1[6] = (_Float16)v1.z; af1[7] = (_Float16)v1.w;
    __syncthreads();
#pragma unroll
    for (int j = 0; j < 4; ++j) {
      f16x8 bf = read_B(Bs, wn + j * 16 + lrow, quad);
      acc[0][j] = __builtin_amdgcn_mfma_f32_16x16x32_f16(af0, bf, acc[0][j], 0, 0, 0);
      acc[1][j] = __builtin_amdgcn_mfma_f32_16x16x32_f16(af1, bf, acc[1][j], 0, 0, 0);
    }
    __syncthreads();
  }
#pragma unroll
  for (int i = 0; i < 2; ++i) {
    int rb = wm + i * 16 + quad * 4;
#pragma unroll
    for (int j = 0; j < 4; ++j) {
      int col = wn + j * 16 + lrow;
      float bv = bb[col];
#pragma unroll
      for (int reg = 0; reg < 4; ++reg) {
        Hs[(rb + reg) * 266 + col] = (_Float16)fmaxf(acc[i][j][reg] + bv, 0.f);
        acc[i][j][reg] = 0.f;
      }
    }
  }
  __syncthreads();

#pragma unroll
  for (int kc = 0; kc < 8; ++kc) {
    stage_tile<256, 8>(Wb, kc * 32, 256, Bs, wave, lane);
    f16x8 af0 = *(const f16x8*)(Hs + (wm + lrow) * 266 + kc * 32 + quad * 8);
    f16x8 af1 = *(const f16x8*)(Hs + (wm + 16 + lrow) * 266 + kc * 32 + quad * 8);
    __syncthreads();
#pragma unroll
    for (int j = 0; j < 4; ++j) {
      f16x8 bf = read_B(Bs, wn + j * 16 + lrow, quad);
      acc[0][j] = __builtin_amdgcn_mfma_f32_16x16x32_f16(af0, bf, acc[0][j], 0, 0, 0);
      acc[1][j] = __builtin_amdgcn_mfma_f32_16x16x32_f16(af1, bf, acc[1][j], 0, 0, 0);
    }
    __syncthreads();
  }
  _Float16* Mo = Mh + (size_t)z * (N_NODES * D);
#pragma unroll
  for (int i = 0; i < 2; ++i) {
    int rb = m0 + wm + i * 16 + quad * 4;
#pragma unroll
    for (int j = 0; j < 4; ++j) {
      int col = wn + j * 16 + lrow;
      float bv = bb[col];
#pragma unroll
      for (int reg = 0; reg < 4; ++reg) {
        int gm = rb + reg;
        if (gm < N_NODES)
          Mo[(size_t)gm * D + col] = (_Float16)fmaxf(acc[i][j][reg] + bv, 0.f);
      }
    }
  }
}

// ---------- tail_mega: agg + gates GEMM + LSTM + 3-layer MLP, one block per 16 rows ----------
// grid 625 x 256 thr (4 waves). All intermediates in LDS; weights LDS-staged per k-chunk.
__global__ __launch_bounds__(256) void tail_mega(
    const int* __restrict__ offs, const unsigned int* __restrict__ rowoff,
    const _Float16* __restrict__ Mh,
    const _Float16* __restrict__ Wg, const float* __restrict__ bg,
    const _Float16* __restrict__ W1h, const float* __restrict__ b1,
    const _Float16* __restrict__ W2h, const float* __restrict__ b2,
    const _Float16* __restrict__ W3h, const float* __restrict__ b3,
    float* __restrict__ out)
{
  __shared__ alignas(16) _Float16 Ws[768 * 32];  // 49,152 B (max: Wg chunk)
  __shared__ _Float16 Agg[16 * 266];             //  8,512
  __shared__ _Float16 Hn[16 * 266];              //  8,512
  __shared__ _Float16 Xs[16 * 138];              //  4,416
  __shared__ _Float16 X2s[16 * 138];             //  4,416
  const int t = threadIdx.x;
  const int wave = t >> 6, lane = t & 63;
  const int quad = lane >> 4, lrow = lane & 15;
  const int r0 = blockIdx.x * 16;                // 625*16 == 10000

  // ---- Phase A: aggregate M rows for this block's 16 nodes (4 nodes/wave) ----
#pragma unroll
  for (int nn = 0; nn < 4; ++nn) {
    const int node = r0 + wave * 4 + nn;
    const int beg = offs[node], end = offs[node + 1];
    float a0 = 0.f, a1 = 0.f, a2 = 0.f, a3 = 0.f;
    int j = beg;
    for (; j + 1 < end; j += 2) {
      unsigned int o0 = rowoff[j], o1 = rowoff[j + 1];
      f16x4 v0 = *(const f16x4*)(Mh + (size_t)o0 + lane * 4);
      f16x4 v1 = *(const f16x4*)(Mh + (size_t)o1 + lane * 4);
      a0 += (float)v0[0] + (float)v1[0];
      a1 += (float)v0[1] + (float)v1[1];
      a2 += (float)v0[2] + (float)v1[2];
      a3 += (float)v0[3] + (float)v1[3];
    }
    if (j < end) {
      unsigned int o0 = rowoff[j];
      f16x4 v0 = *(const f16x4*)(Mh + (size_t)o0 + lane * 4);
      a0 += (float)v0[0]; a1 += (float)v0[1]; a2 += (float)v0[2]; a3 += (float)v0[3];
    }
    f16x4 o;
    o[0] = (_Float16)a0; o[1] = (_Float16)a1; o[2] = (_Float16)a2; o[3] = (_Float16)a3;
    *(f16x4*)(Agg + (wave * 4 + nn) * 266 + lane * 4) = o;
  }
  __syncthreads();

  // ---- Phase B: gates = Agg @ Wg^T (+bg) with LSTM epilogue -> Hn (LDS) ----
  {
    f16x8 af[8];
#pragma unroll
    for (int kc = 0; kc < 8; ++kc)
      af[kc] = *(const f16x8*)(Agg + lrow * 266 + kc * 32 + quad * 8);
    f32x4 acc[12];
#pragma unroll
    for (int j = 0; j < 12; ++j) acc[j] = (f32x4)0.0f;
#pragma unroll
    for (int kc = 0; kc < 8; ++kc) {
      stage_tile<768, 4>(Wg, kc * 32, 256, Ws, wave, lane);
      __syncthreads();
#pragma unroll
      for (int j = 0; j < 12; ++j) {
        f16x8 bf = read_B(Ws, (wave * 12 + j) * 16 + lrow, quad);
        acc[j] = __builtin_amdgcn_mfma_f32_16x16x32_f16(af[kc], bf, acc[j], 0, 0, 0);
      }
      __syncthreads();
    }
    // LSTM: tiles (3p, 3p+1, 3p+2) are (i,g,o) of d-group (wave*4+p)
#pragma unroll
    for (int p = 0; p < 4; ++p) {
      float bvi = bg[(wave * 12 + 3 * p + 0) * 16 + lrow];
      float bvg = bg[(wave * 12 + 3 * p + 1) * 16 + lrow];
      float bvo = bg[(wave * 12 + 3 * p + 2) * 16 + lrow];
      int dcol = (wave * 4 + p) * 16 + lrow;
#pragma unroll
      for (int reg = 0; reg < 4; ++reg) {
        float vi = acc[3 * p + 0][reg] + bvi;
        float vg = acc[3 * p + 1][reg] + bvg;
        float vo = acc[3 * p + 2][reg] + bvo;
        float c = fast_sigmoid(vi) * fast_tanh(vg);
        Hn[(quad * 4 + reg) * 266 + dcol] = (_Float16)(fast_sigmoid(vo) * fast_tanh(c));
      }
    }
  }
  __syncthreads();

  // ---- Phase C: x1 = relu(Hn @ W1^T + b1): N=128, K=256; wave covers 32 cols ----
  {
    f16x8 af[8];
#pragma unroll
    for (int kc = 0; kc < 8; ++kc)
      af[kc] = *(const f16x8*)(Hn + lrow * 266 + kc * 32 + quad * 8);
    f32x4 acc[2];
    acc[0] = (f32x4)0.0f; acc[1] = (f32x4)0.0f;
#pragma unroll
    for (int kc = 0; kc < 8; ++kc) {
      stage_tile<128, 4>(W1h, kc * 32, 256, Ws, wave, lane);
      __syncthreads();
#pragma unroll
      for (int j = 0; j < 2; ++j) {
        f16x8 bf = read_B(Ws, wave * 32 + j * 16 + lrow, quad);
        acc[j] = __builtin_amdgcn_mfma_f32_16x16x32_f16(af[kc], bf, acc[j], 0, 0, 0);
      }
      __syncthreads();
    }
#pragma unroll
    for (int j = 0; j < 2; ++j) {
      int col = wave * 32 + j * 16 + lrow;
      float bv = b1[col];
#pragma unroll
      for (int reg = 0; reg < 4; ++reg)
        Xs[(quad * 4 + reg) * 138 + col] = (_Float16)fmaxf(acc[j][reg] + bv, 0.f);
    }
  }
  __syncthreads();

  // ---- Phase D: x2 = relu(Xs @ W2^T + b2): N=128, K=128 ----
  {
    f16x8 af[4];
#pragma unroll
    for (int kc = 0; kc < 4; ++kc)
      af[kc] = *(const f16x8*)(Xs + lrow * 138 + kc * 32 + quad * 8);
    f32x4 acc[2];
    acc[0] = (f32x4)0.0f; acc[1] = (f32x4)0.0f;
#pragma unroll
    for (int kc = 0; kc < 4; ++kc) {
      stage_tile<128, 4>(W2h, kc * 32, 128, Ws, wave, lane);
      __syncthreads();
#pragma unroll
      for (int j = 0; j < 2; ++j) {
        f16x8 bf = read_B(Ws, wave * 32 + j * 16 + lrow, quad);
        acc[j] = __builtin_amdgcn_mfma_f32_16x16x32_f16(af[kc], bf, acc[j], 0, 0, 0);
      }
      __syncthreads();
    }
#pragma unroll
    for (int j = 0; j < 2; ++j) {
      int col = wave * 32 + j * 16 + lrow;
      float bv = b2[col];
#pragma unroll
      for (int reg = 0; reg < 4; ++reg)
        X2s[(quad * 4 + reg) * 138 + col] = (_Float16)fmaxf(acc[j][reg] + bv, 0.f);
    }
  }
  __syncthreads();

  // ---- Phase E: out = X2s @ W3^T + b3: N=256, K=128, fp32 out; wave covers 64 cols ----
  {
    f16x8 af[4];
#pragma unroll
    for (int kc = 0; kc < 4; ++kc)
      af[kc] = *(const f16x8*)(X2s + lrow * 138 + kc * 32 + quad * 8);
    f32x4 acc[4];
#pragma unroll
    for (int j = 0; j < 4; ++j) acc[j] = (f32x4)0.0f;
#pragma unroll
    for (int kc = 0; kc < 4; ++kc) {
      stage_tile<256, 4>(W3h, kc * 32, 128, Ws, wave, lane);
      __syncthreads();
#pragma unroll
      for (int j = 0; j < 4; ++j) {
        f16x8 bf = read_B(Ws, wave * 64 + j * 16 + lrow, quad);
        acc[j] = __builtin_amdgcn_mfma_f32_16x16x32_f16(af[kc], bf, acc[j], 0, 0, 0);
      }
      __syncthreads();
    }
#pragma unroll
    for (int j = 0; j < 4; ++j) {
      int col = wave * 64 + j * 16 + lrow;
      float bv = b3[col];
#pragma unroll
      for (int reg = 0; reg < 4; ++reg)
        out[(size_t)(r0 + quad * 4 + reg) * 256 + col] = acc[j][reg] + bv;
    }
  }
}

// ---------- launch ----------
extern "C" void kernel_launch(void* const* d_in, const int* in_sizes, int n_in,
                              void* d_out, int out_size, void* d_ws, size_t ws_size,
                              hipStream_t stream) {
  const float* feat  = (const float*)d_in[0];
  const int* src = (const int*)d_in[1];
  const int* dst = (const int*)d_in[2];
  const int* rel = (const int*)d_in[3];
  const float* W_rel = (const float*)d_in[4];
  const float* b_rel = (const float*)d_in[5];
  const float* W_ih  = (const float*)d_in[6];
  const float* b_ih  = (const float*)d_in[7];
  const float* b_hh  = (const float*)d_in[8];
  const float* W1 = (const float*)d_in[9];
  const float* b1 = (const float*)d_in[10];
  const float* W2 = (const float*)d_in[11];
  const float* b2 = (const float*)d_in[12];
  const float* W3 = (const float*)d_in[13];
  const float* b3 = (const float*)d_in[14];
  float* out = (float*)d_out;

  char* ws = (char*)d_ws;
  _Float16* Mh = (_Float16*)(ws);                  // 10,240,000 B (2 rel slabs)
  char* wsb = ws + 10240000;
  _Float16* W_relh = (_Float16*)(wsb);             // 262,144
  _Float16* Wg     = (_Float16*)(wsb + 262144);    // 393,216
  _Float16* W1h    = (_Float16*)(wsb + 655360);    // 65,536
  _Float16* W2h    = (_Float16*)(wsb + 720896);    // 32,768
  _Float16* W3h    = (_Float16*)(wsb + 753664);    // 65,536
  float*    bg     = (float*)(wsb + 819200);       // 3,072
  int*      cnt    = (int*)(wsb + 822272);         // 40,000
  int*      offs   = (int*)(wsb + 862272);         // 40,004 (+pad)
  int*      cursors= (int*)(wsb + 902280);         // 40,000
  unsigned int* rowoff = (unsigned int*)(wsb + 942280);  // 1,280,000

  (void)hipMemsetAsync(cnt, 0, N_NODES * sizeof(int), stream);
  prep_kernel<<<2853, 256, 0, stream>>>(W_rel, W_ih, b_ih, b_hh, W1, W2, W3,
                                        dst, cnt, W_relh, Wg, bg, W1h, W2h, W3h);
  scan_kernel<<<1, 1024, 0, stream>>>(cnt, offs, cursors, N_NODES);
  fill_kernel<<<1250, 256, 0, stream>>>(dst, src, rel, cursors, rowoff);

  // fused edge NN (both layers, both relations)
  edge_fused<<<dim3(157, 2), 512, 0, stream>>>(feat, W_relh, b_rel, Mh);

  // fused agg + gates + LSTM + MLP -> out
  tail_mega<<<625, 256, 0, stream>>>(offs, rowoff, Mh, Wg, bg,
                                     W1h, b1, W2h, b2, W3h, b3, out);
}